// Round 4
// baseline (1451.420 us; speedup 1.0000x reference)
//
#include <hip/hip_runtime.h>
#include <hip/hip_bf16.h>
#include <math.h>
#include <stdint.h>

typedef unsigned short u16;
typedef __attribute__((ext_vector_type(8))) short short8;
typedef __attribute__((ext_vector_type(4))) float floatx4;

#define NB 8
#define P0 4608
#define C0 1024
#define H0 4096

// mode: 0 = inputs/outputs are float32, 1 = bf16
__global__ void detect_mode_kernel(const uint32_t* __restrict__ pe_words, int* __restrict__ mode) {
  *mode = (pe_words[64] != 0u) ? 1 : 0;
}

__device__ __forceinline__ float load_in(const void* p, size_t idx, int mode) {
  if (mode) return __bfloat162float(((const __hip_bfloat16*)p)[idx]);
  return ((const float*)p)[idx];
}

// ---------------- metric: mean over 16 heads of 64-dim chunks, L2 normalize ----------------
__global__ void metric_in_kernel(const void* __restrict__ x, const void* __restrict__ pos,
                                 const int* __restrict__ mode, float* __restrict__ m) {
  int tok = blockIdx.x * 4 + (threadIdx.x >> 6);
  int lane = threadIdx.x & 63;
  if (tok >= NB * P0) return;
  int b = tok / P0, t = tok - b * P0;
  int md = *mode;
  size_t xbase = ((size_t)b * P0 + t) * C0 + lane;
  size_t pbase = (size_t)t * C0 + lane;
  float s = 0.f;
#pragma unroll
  for (int h = 0; h < 16; ++h)
    s += load_in(x, xbase + h * 64, md) + load_in(pos, pbase + h * 64, md);
  s *= (1.f / 16.f);
  float sq = s * s;
#pragma unroll
  for (int off = 1; off < 64; off <<= 1) sq += __shfl_xor(sq, off, 64);
  m[(size_t)tok * 64 + lane] = s / sqrtf(sq);
}

__global__ void metric_f32_kernel(const float* __restrict__ x, float* __restrict__ m, int p) {
  int tok = blockIdx.x * 4 + (threadIdx.x >> 6);
  int lane = threadIdx.x & 63;
  if (tok >= NB * p) return;
  const float* xr = x + (size_t)tok * C0 + lane;
  float s = 0.f;
#pragma unroll
  for (int h = 0; h < 16; ++h) s += xr[h * 64];
  s *= (1.f / 16.f);
  float sq = s * s;
#pragma unroll
  for (int off = 1; off < 64; off <<= 1) sq += __shfl_xor(sq, off, 64);
  m[(size_t)tok * 64 + lane] = s / sqrtf(sq);
}

// ---------------- scores (fp32) + per-(row, j-block) argmax partials ----------------
__global__ __launch_bounds__(256) void score_kernel(const float* __restrict__ M_,
                                                    int p, int p2, int jT,
                                                    float* __restrict__ pm,
                                                    int* __restrict__ pi) {
  __shared__ __align__(16) float4 As[128 * 8];
  __shared__ __align__(16) float4 Bs[128 * 8];
  const int bi = blockIdx.x, ii = blockIdx.y, b = blockIdx.z;
  const int t = threadIdx.x;
  const float* Mb = M_ + (size_t)b * p * 64;
  const int ty = t >> 4, tx = t & 15;
  float s[8][8];
#pragma unroll
  for (int u = 0; u < 8; ++u)
#pragma unroll
    for (int v = 0; v < 8; ++v) s[u][v] = 0.f;

  const int d4 = t & 7, r0 = t >> 3;
  for (int stage = 0; stage < 2; ++stage) {
#pragma unroll
    for (int pass = 0; pass < 4; ++pass) {
      int row = r0 + pass * 32;
      int sw = (d4 + (row >> 3)) & 7;
      int ar = 2 * (ii * 128 + row);
      if (ar > p - 2) ar = p - 2;
      int br = 2 * (bi * 128 + row) + 1;
      if (br > p - 1) br = p - 1;
      As[row * 8 + sw] = *(const float4*)(Mb + (size_t)ar * 64 + stage * 32 + d4 * 4);
      Bs[row * 8 + sw] = *(const float4*)(Mb + (size_t)br * 64 + stage * 32 + d4 * 4);
    }
    __syncthreads();
    for (int k4 = 0; k4 < 8; ++k4) {
      float4 av[8], bv[8];
#pragma unroll
      for (int u = 0; u < 8; ++u) av[u] = As[(ty * 8 + u) * 8 + ((k4 + ty) & 7)];
#pragma unroll
      for (int v = 0; v < 8; ++v) bv[v] = Bs[(tx * 8 + v) * 8 + ((k4 + tx) & 7)];
#pragma unroll
      for (int u = 0; u < 8; ++u)
#pragma unroll
        for (int v = 0; v < 8; ++v) {
          s[u][v] += av[u].x * bv[v].x;
          s[u][v] += av[u].y * bv[v].y;
          s[u][v] += av[u].z * bv[v].z;
          s[u][v] += av[u].w * bv[v].w;
        }
    }
    __syncthreads();
  }

#pragma unroll
  for (int u = 0; u < 8; ++u) {
    int i = ii * 128 + ty * 8 + u;
    if (i >= p2) continue;
    float bm = -INFINITY;
    int bj = 0x7fffffff;
#pragma unroll
    for (int v = 0; v < 8; ++v) {
      int j = bi * 128 + tx * 8 + v;
      if (j < p2 && s[u][v] > bm) { bm = s[u][v]; bj = j; }
    }
#pragma unroll
    for (int mk = 1; mk < 16; mk <<= 1) {
      float om = __shfl_xor(bm, mk, 64);
      int oj = __shfl_xor(bj, mk, 64);
      if (om > bm || (om == bm && oj < bj)) { bm = om; bj = oj; }
    }
    if (tx == 0) {
      size_t o = ((size_t)b * 2304 + i) * jT + bi;
      pm[o] = bm;
      pi[o] = bj;
    }
  }
}

__global__ void argmax_combine_kernel(const float* __restrict__ pm, const int* __restrict__ pi,
                                      int p2, int jT, float* __restrict__ nmax,
                                      int* __restrict__ nidx) {
  int g = blockIdx.x * 256 + threadIdx.x;
  if (g >= NB * p2) return;
  int b = g / p2, i = g - b * p2;
  const float* r = pm + ((size_t)b * 2304 + i) * jT;
  const int* ri = pi + ((size_t)b * 2304 + i) * jT;
  float best = r[0];
  int bidx = ri[0];
  for (int k = 1; k < jT; ++k) {
    if (r[k] > best || (r[k] == best && ri[k] < bidx)) { best = r[k]; bidx = ri[k]; }
  }
  nmax[g] = best;
  nidx[g] = bidx;
}

// ---------------- merge (all-evens-merge case, r == p/2) ----------------
__global__ void merge_init_in(const void* __restrict__ x, const void* __restrict__ pos,
                              const int* __restrict__ mode, float* __restrict__ xo,
                              float* __restrict__ so, int p2) {
  int tj = blockIdx.x;
  int b = tj / p2, j = tj - b * p2;
  int c = threadIdx.x * 4;
  int md = *mode;
  size_t xb = ((size_t)b * P0 + 2 * j + 1) * C0 + c;
  size_t pb = (size_t)(2 * j + 1) * C0 + c;
  float4 o;
  o.x = load_in(x, xb + 0, md) + load_in(pos, pb + 0, md);
  o.y = load_in(x, xb + 1, md) + load_in(pos, pb + 1, md);
  o.z = load_in(x, xb + 2, md) + load_in(pos, pb + 2, md);
  o.w = load_in(x, xb + 3, md) + load_in(pos, pb + 3, md);
  *(float4*)(xo + (size_t)tj * C0 + c) = o;
  if (threadIdx.x == 0) so[tj] = 1.f;
}

__global__ void merge_scatter_in(const void* __restrict__ x, const void* __restrict__ pos,
                                 const int* __restrict__ mode, const int* __restrict__ nidx,
                                 float* __restrict__ xo, float* __restrict__ so, int p2) {
  int ti = blockIdx.x;
  int b = ti / p2, i = ti - b * p2;
  int c = threadIdx.x * 4;
  int md = *mode;
  int dst = nidx[ti];
  if ((unsigned)dst >= (unsigned)p2) dst = 0;
  size_t xb = ((size_t)b * P0 + 2 * i) * C0 + c;
  size_t pb = (size_t)(2 * i) * C0 + c;
  float* out = xo + ((size_t)b * p2 + dst) * C0 + c;
  atomicAdd(out + 0, load_in(x, xb + 0, md) + load_in(pos, pb + 0, md));
  atomicAdd(out + 1, load_in(x, xb + 1, md) + load_in(pos, pb + 1, md));
  atomicAdd(out + 2, load_in(x, xb + 2, md) + load_in(pos, pb + 2, md));
  atomicAdd(out + 3, load_in(x, xb + 3, md) + load_in(pos, pb + 3, md));
  if (threadIdx.x == 0) atomicAdd(so + (size_t)b * p2 + dst, 1.f);
}

__global__ void merge_init_f(const float* __restrict__ xi, const float* __restrict__ si,
                             float* __restrict__ xo, float* __restrict__ so, int p, int p2) {
  int tj = blockIdx.x;
  int b = tj / p2, j = tj - b * p2;
  int c = threadIdx.x * 4;
  float sz = si[(size_t)b * p + 2 * j + 1];
  float4 v = *(const float4*)(xi + ((size_t)b * p + 2 * j + 1) * C0 + c);
  float4 o = {v.x * sz, v.y * sz, v.z * sz, v.w * sz};
  *(float4*)(xo + (size_t)tj * C0 + c) = o;
  if (threadIdx.x == 0) so[tj] = sz;
}

__global__ void merge_scatter_f(const float* __restrict__ xi, const float* __restrict__ si,
                                const int* __restrict__ nidx, float* __restrict__ xo,
                                float* __restrict__ so, int p, int p2) {
  int ti = blockIdx.x;
  int b = ti / p2, i = ti - b * p2;
  int c = threadIdx.x * 4;
  int dst = nidx[ti];
  if ((unsigned)dst >= (unsigned)p2) dst = 0;
  float sz = si[(size_t)b * p + 2 * i];
  float4 v = *(const float4*)(xi + ((size_t)b * p + 2 * i) * C0 + c);
  float* out = xo + ((size_t)b * p2 + dst) * C0 + c;
  atomicAdd(out + 0, v.x * sz);
  atomicAdd(out + 1, v.y * sz);
  atomicAdd(out + 2, v.z * sz);
  atomicAdd(out + 3, v.w * sz);
  if (threadIdx.x == 0) atomicAdd(so + (size_t)b * p2 + dst, sz);
}

__global__ void merge_div(float* __restrict__ xo, const float* __restrict__ so, int p2) {
  int tj = blockIdx.x;
  int c = threadIdx.x * 4;
  float sz = so[tj];
  float4 v = *(float4*)(xo + (size_t)tj * C0 + c);
  v.x /= sz; v.y /= sz; v.z /= sz; v.w /= sz;
  *(float4*)(xo + (size_t)tj * C0 + c) = v;
}

// ---------------- last iteration (p=144, p2=72, r=16): stable descending rank ----------------
__global__ void rank_kernel(const float* __restrict__ nmax, const int* __restrict__ nidx,
                            int* __restrict__ unm_map, int* __restrict__ src_ord,
                            int* __restrict__ src_dst) {
  int b = blockIdx.x;
  int i = threadIdx.x;
  __shared__ float v[72];
  __shared__ int nx[72];
  if (i < 72) { v[i] = nmax[b * 72 + i]; nx[i] = nidx[b * 72 + i]; }
  __syncthreads();
  if (i < 72) {
    float vi = v[i];
    int rank = 0;
    for (int k = 0; k < 72; ++k) {
      float vk = v[k];
      rank += (vk > vi) || (vk == vi && k < i);
    }
    if (rank < 16) {
      int d = nx[i];
      if ((unsigned)d >= 72u) d = 0;
      src_ord[b * 16 + rank] = i;
      src_dst[b * 16 + rank] = d;
    } else {
      unm_map[b * 56 + (rank - 16)] = i;
    }
  }
}

__global__ void final_init(const float* __restrict__ x5, const float* __restrict__ s5,
                           const int* __restrict__ unm_map, float* __restrict__ xf,
                           float* __restrict__ sf) {
  int bt = blockIdx.x;
  int b = bt >> 7, tk = bt & 127;
  int c = threadIdx.x * 4;
  float4 o;
  float szo;
  if (tk < 56) {
    int se = unm_map[b * 56 + tk];
    if ((unsigned)se >= 72u) se = 0;
    o = *(const float4*)(x5 + ((size_t)b * 144 + 2 * se) * C0 + c);
    szo = 1.f;
  } else {
    int j = tk - 56;
    float sz = s5[b * 144 + 2 * j + 1];
    float4 v = *(const float4*)(x5 + ((size_t)b * 144 + 2 * j + 1) * C0 + c);
    o.x = v.x * sz; o.y = v.y * sz; o.z = v.z * sz; o.w = v.w * sz;
    szo = sz;
  }
  *(float4*)(xf + (size_t)bt * C0 + c) = o;
  if (threadIdx.x == 0) sf[bt] = szo;
}

__global__ void final_scatter(const float* __restrict__ x5, const float* __restrict__ s5,
                              const int* __restrict__ src_ord, const int* __restrict__ src_dst,
                              float* __restrict__ xf, float* __restrict__ sf) {
  int bk = blockIdx.x;
  int b = bk >> 4, k = bk & 15;
  int c = threadIdx.x * 4;
  int st = src_ord[b * 16 + k], dst = src_dst[b * 16 + k];
  if ((unsigned)st >= 72u) st = 0;
  if ((unsigned)dst >= 72u) dst = 0;
  float sz = s5[b * 144 + 2 * st];
  float4 v = *(const float4*)(x5 + ((size_t)b * 144 + 2 * st) * C0 + c);
  float* out = xf + ((size_t)(b * 128 + 56 + dst)) * C0 + c;
  atomicAdd(out + 0, v.x * sz);
  atomicAdd(out + 1, v.y * sz);
  atomicAdd(out + 2, v.z * sz);
  atomicAdd(out + 3, v.w * sz);
  if (threadIdx.x == 0) atomicAdd(sf + b * 128 + 56 + dst, sz);
}

__global__ void final_div_cvt(const float* __restrict__ xf, const float* __restrict__ sf,
                              __hip_bfloat16* __restrict__ xb) {
  int bt = blockIdx.x;
  int c = threadIdx.x * 4;
  float sz = sf[bt];
  float4 v = *(const float4*)(xf + (size_t)bt * C0 + c);
  __hip_bfloat16* o = xb + (size_t)bt * C0 + c;
  o[0] = __float2bfloat16(v.x / sz);
  o[1] = __float2bfloat16(v.y / sz);
  o[2] = __float2bfloat16(v.z / sz);
  o[3] = __float2bfloat16(v.w / sz);
}

// ---------------- dual-dtype transpose (KxN -> NxK), output bf16 ----------------
__global__ void transpose_in(const void* __restrict__ in, const int* __restrict__ mode,
                             u16* __restrict__ out, int K, int N) {
  __shared__ u16 tile[64][65];
  int n0 = blockIdx.x * 64, k0 = blockIdx.y * 64;
  int t = threadIdx.x;
  int md = *mode;
  int r = t >> 4, c4 = (t & 15) * 4;
#pragma unroll
  for (int pass = 0; pass < 4; ++pass) {
    int row = r + pass * 16;
#pragma unroll
    for (int e = 0; e < 4; ++e) {
      float v = load_in(in, (size_t)(k0 + row) * N + n0 + c4 + e, md);
      __hip_bfloat16 bv = __float2bfloat16(v);
      tile[row][c4 + e] = *(u16*)&bv;
    }
  }
  __syncthreads();
#pragma unroll
  for (int pass = 0; pass < 4; ++pass) {
    int row = r + pass * 16;
    ushort4 o;
    o.x = tile[c4][row]; o.y = tile[c4 + 1][row]; o.z = tile[c4 + 2][row]; o.w = tile[c4 + 3][row];
    *(ushort4*)(out + (size_t)(n0 + row) * K + k0 + c4) = o;
  }
}

// ---------------- bf16 MFMA GEMM, B pre-transposed (NT) ----------------
// C[M,N] = A[M,K]*BT[N,K]^T + bias, optional exact GELU.
// out_sel==0: always store bf16 (u16). out_sel==1: store per detected mode.
__global__ __launch_bounds__(256) void gemm_bt(const u16* __restrict__ A,
                                               const u16* __restrict__ BT,
                                               const void* __restrict__ bias,
                                               const int* __restrict__ mode,
                                               void* __restrict__ C, int M, int N,
                                               int K, int act, int out_sel) {
  __shared__ __align__(16) u16 As[128 * 64];
  __shared__ __align__(16) u16 Bs[128 * 64];
  const int t = threadIdx.x, w = t >> 6, L = t & 63;
  const int m0 = blockIdx.y * 128, n0 = blockIdx.x * 128;
  const int wr = w >> 1, wc = w & 1;
  const int md = *mode;
  floatx4 acc[4][4];
#pragma unroll
  for (int a = 0; a < 4; ++a)
#pragma unroll
    for (int bb = 0; bb < 4; ++bb) acc[a][bb] = (floatx4){0.f, 0.f, 0.f, 0.f};
  const int fr = L & 15, fq = (L >> 4) * 8;
  const int srow = t >> 3, sc8 = (t & 7) * 8;
  for (int k0 = 0; k0 < K; k0 += 64) {
#pragma unroll
    for (int q = 0; q < 4; ++q) {
      int row = srow + q * 32;
      *(short8*)(As + row * 64 + sc8) =
          *(const short8*)(A + (size_t)(m0 + row) * K + k0 + sc8);
      *(short8*)(Bs + row * 64 + sc8) =
          *(const short8*)(BT + (size_t)(n0 + row) * K + k0 + sc8);
    }
    __syncthreads();
#pragma unroll
    for (int kh = 0; kh < 2; ++kh) {
      short8 af[4], bfr[4];
#pragma unroll
      for (int mt = 0; mt < 4; ++mt)
        af[mt] = *(const short8*)(As + (wr * 64 + mt * 16 + fr) * 64 + kh * 32 + fq);
#pragma unroll
      for (int nt = 0; nt < 4; ++nt)
        bfr[nt] = *(const short8*)(Bs + (wc * 64 + nt * 16 + fr) * 64 + kh * 32 + fq);
#pragma unroll
      for (int mt = 0; mt < 4; ++mt)
#pragma unroll
        for (int nt = 0; nt < 4; ++nt)
          acc[mt][nt] =
              __builtin_amdgcn_mfma_f32_16x16x32_bf16(af[mt], bfr[nt], acc[mt][nt], 0, 0, 0);
    }
    __syncthreads();
  }
#pragma unroll
  for (int mt = 0; mt < 4; ++mt)
#pragma unroll
    for (int nt = 0; nt < 4; ++nt) {
      int n = n0 + wc * 64 + nt * 16 + fr;
      float bz = load_in(bias, n, md);
#pragma unroll
      for (int rr = 0; rr < 4; ++rr) {
        int m = m0 + wr * 64 + mt * 16 + (L >> 4) * 4 + rr;
        float v = acc[mt][nt][rr] + bz;
        if (act) v = 0.5f * v * (1.f + erff(v * 0.70710678118654752f));
        size_t idx = (size_t)m * N + n;
        if (out_sel == 0 || md) {
          __hip_bfloat16 bv = __float2bfloat16(v);
          ((u16*)C)[idx] = *(u16*)&bv;
        } else {
          ((float*)C)[idx] = v;
        }
      }
    }
}

// ---------------- host ----------------
extern "C" void kernel_launch(void* const* d_in, const int* in_sizes, int n_in, void* d_out,
                              int out_size, void* d_ws, size_t ws_size, hipStream_t stream) {
  const void* x = d_in[0];
  const void* pe = d_in[1];
  const void* W1 = d_in[2];
  const void* b1 = d_in[3];
  const void* W2 = d_in[4];
  const void* b2 = d_in[5];

  char* base = (char*)d_ws;
  size_t off = 0;
  auto alloc = [&](size_t bytes) -> void* {
    void* p = base + off;
    off += (bytes + 255) & ~(size_t)255;
    return p;
  };
  int* mode = (int*)alloc(256);
  float* mbuf = (float*)alloc((size_t)NB * 4608 * 64 * 4);
  float* pm = (float*)alloc((size_t)NB * 2304 * 18 * 4);
  int* pi = (int*)alloc((size_t)NB * 2304 * 18 * 4);
  float* nmax = (float*)alloc((size_t)NB * 2304 * 4);
  int* nidx = (int*)alloc((size_t)NB * 2304 * 4);
  float* bufA = (float*)alloc((size_t)NB * 2304 * C0 * 4);
  float* bufB = (float*)alloc((size_t)NB * 1152 * C0 * 4);
  float* s1 = (float*)alloc((size_t)NB * 2304 * 4);
  float* s2 = (float*)alloc((size_t)NB * 1152 * 4);
  float* s3 = (float*)alloc((size_t)NB * 576 * 4);
  float* s4 = (float*)alloc((size_t)NB * 288 * 4);
  float* s5 = (float*)alloc((size_t)NB * 144 * 4);
  float* sf = (float*)alloc((size_t)NB * 128 * 4);
  int* unm_map = (int*)alloc((size_t)NB * 56 * 4);
  int* src_ord = (int*)alloc((size_t)NB * 16 * 4);
  int* src_dst = (int*)alloc((size_t)NB * 16 * 4);
  u16* xfb = (u16*)alloc((size_t)NB * 128 * C0 * 2);
  u16* hbuf = (u16*)alloc((size_t)1024 * H0 * 2);
  u16* w1t = (u16*)alloc((size_t)H0 * C0 * 2);
  u16* w2t = (u16*)alloc((size_t)H0 * H0 * 2);
  if (off > ws_size) return;

  float* x1 = bufA;
  float* x2 = bufB;
  float* x3 = bufA;
  float* x4 = bufB;
  float* x5 = bufA;
  float* xf = bufB;

  detect_mode_kernel<<<1, 1, 0, stream>>>((const uint32_t*)pe, mode);

  // weight transposes (W is KxN row-major -> NxK bf16)
  transpose_in<<<dim3(4096 / 64, 1024 / 64), 256, 0, stream>>>(W1, mode, w1t, 1024, 4096);
  transpose_in<<<dim3(4096 / 64, 4096 / 64), 256, 0, stream>>>(W2, mode, w2t, 4096, 4096);

  // ---- iter 1: p=4608 -> p2=2304 (all evens merge)
  metric_in_kernel<<<NB * P0 / 4, 256, 0, stream>>>(x, pe, mode, mbuf);
  score_kernel<<<dim3(18, 18, NB), 256, 0, stream>>>(mbuf, 4608, 2304, 18, pm, pi);
  argmax_combine_kernel<<<(NB * 2304 + 255) / 256, 256, 0, stream>>>(pm, pi, 2304, 18, nmax, nidx);
  merge_init_in<<<NB * 2304, 256, 0, stream>>>(x, pe, mode, x1, s1, 2304);
  merge_scatter_in<<<NB * 2304, 256, 0, stream>>>(x, pe, mode, nidx, x1, s1, 2304);
  merge_div<<<NB * 2304, 256, 0, stream>>>(x1, s1, 2304);

  // ---- iters 2..5 (generic all-evens-merge)
  float* xs_in[4] = {x1, x2, x3, x4};
  float* ss_in[4] = {s1, s2, s3, s4};
  float* xs_out[4] = {x2, x3, x4, x5};
  float* ss_out[4] = {s2, s3, s4, s5};
  int ps[5] = {2304, 1152, 576, 288, 144};
  for (int it = 0; it < 4; ++it) {
    int p = ps[it], p2 = ps[it + 1];
    int iT = (p2 + 127) / 128, jT = (p2 + 127) / 128;
    metric_f32_kernel<<<NB * p / 4, 256, 0, stream>>>(xs_in[it], mbuf, p);
    score_kernel<<<dim3(jT, iT, NB), 256, 0, stream>>>(mbuf, p, p2, jT, pm, pi);
    argmax_combine_kernel<<<(NB * p2 + 255) / 256, 256, 0, stream>>>(pm, pi, p2, jT, nmax, nidx);
    merge_init_f<<<NB * p2, 256, 0, stream>>>(xs_in[it], ss_in[it], xs_out[it], ss_out[it], p, p2);
    merge_scatter_f<<<NB * p2, 256, 0, stream>>>(xs_in[it], ss_in[it], nidx, xs_out[it],
                                                 ss_out[it], p, p2);
    merge_div<<<NB * p2, 256, 0, stream>>>(xs_out[it], ss_out[it], p2);
  }

  // ---- iter 6: p=144, p2=72, r=16 -> 128 tokens
  metric_f32_kernel<<<NB * 144 / 4, 256, 0, stream>>>(x5, mbuf, 144);
  score_kernel<<<dim3(1, 1, NB), 256, 0, stream>>>(mbuf, 144, 72, 1, pm, pi);
  argmax_combine_kernel<<<(NB * 72 + 255) / 256, 256, 0, stream>>>(pm, pi, 72, 1, nmax, nidx);
  rank_kernel<<<NB, 128, 0, stream>>>(nmax, nidx, unm_map, src_ord, src_dst);
  final_init<<<NB * 128, 256, 0, stream>>>(x5, s5, unm_map, xf, sf);
  final_scatter<<<NB * 16, 256, 0, stream>>>(x5, s5, src_ord, src_dst, xf, sf);
  final_div_cvt<<<NB * 128, 256, 0, stream>>>(xf, sf, (__hip_bfloat16*)xfb);

  // ---- MLP: h = gelu(x@W1 + b1); out = h@W2 + b2
  gemm_bt<<<dim3(4096 / 128, 1024 / 128), 256, 0, stream>>>(xfb, w1t, b1, mode, hbuf, 1024, 4096,
                                                            1024, 1, 0);
  gemm_bt<<<dim3(4096 / 128, 1024 / 128), 256, 0, stream>>>(hbuf, w2t, b2, mode, d_out, 1024,
                                                            4096, 4096, 0, 1);
}